// Round 1
// baseline (2089.551 us; speedup 1.0000x reference)
//
#include <hip/hip_runtime.h>

#define N_NODES 50000
#define N_EDGES 800000
#define MUL0 16
#define MUL1 8
#define DIM_F 40   // 16 + 3*8
#define NRB 16
#define NRD 64
#define W_NUMEL 576

// ---------------------------------------------------------------------------
// Kernel 1: zero the output (harness poisons d_out with 0xAA before each call)
// ---------------------------------------------------------------------------
__global__ void zero_out_kernel(float4* __restrict__ p, int n4) {
    int i = blockIdx.x * blockDim.x + threadIdx.x;
    if (i < n4) p[i] = make_float4(0.f, 0.f, 0.f, 0.f);
}

// ---------------------------------------------------------------------------
// Kernel 2: fused per-edge conv. One thread per edge.
//  - emb (16) and h (64) in registers (fully unrolled static indexing)
//  - W1/W2 accessed with wave-uniform addresses -> scalar loads (s_load),
//    inner GEMM is pure v_fma_f32 with SGPR second operand
//  - per-edge x (40) + dot (8) in LDS so the rolled 36-chunk loop can index
//    them dynamically without scratch
//  - 40 atomicAdd per edge into f_out[dst]
// ---------------------------------------------------------------------------
__global__ __launch_bounds__(256) void conv_kernel(
    const float* __restrict__ pos,
    const float* __restrict__ f_in,
    const int*   __restrict__ esrc,
    const int*   __restrict__ edst,
    const float* __restrict__ W1,
    const float* __restrict__ W2,
    float*       __restrict__ f_out)
{
    __shared__ float xsh[256 * 48];   // 48 KB: per-thread [x(40) | dot2(8)]
    const int tid = threadIdx.x;
    const int e   = blockIdx.x * 256 + tid;
    if (e >= N_EDGES) return;

    const int s = esrc[e];
    const int d = edst[e];

    // --- geometry -----------------------------------------------------------
    float px = pos[3*d+0] - pos[3*s+0];
    float py = pos[3*d+1] - pos[3*s+1];
    float pz = pos[3*d+2] - pos[3*s+2];
    float r2 = px*px + py*py + pz*pz + 1e-12f;
    float r  = sqrtf(r2);
    float inv_r = __builtin_amdgcn_rcpf(r);
    float ux = px*inv_r, uy = py*inv_r, uz = pz*inv_r;
    const float SQ3 = 1.7320508075688772f;
    float shx = SQ3*ux, shy = SQ3*uy, shz = SQ3*uz;

    // --- stage x = f_in[src] into LDS --------------------------------------
    float* myx = &xsh[tid * 48];
    {
        const float4* xg4 = reinterpret_cast<const float4*>(f_in + (size_t)s * 40);
        #pragma unroll
        for (int q = 0; q < 10; ++q) {
            float4 v = xg4[q];
            myx[4*q+0] = v.x; myx[4*q+1] = v.y; myx[4*q+2] = v.z; myx[4*q+3] = v.w;
        }
        // dot2[u] = x1[u] . unit   ( == inv_s3 * (x1[u] . sh1) )
        #pragma unroll
        for (int u = 0; u < 8; ++u) {
            float dv = myx[16+3*u+0]*ux + myx[16+3*u+1]*uy + myx[16+3*u+2]*uz;
            myx[40 + u] = dv;
        }
    }

    // --- radial embedding (soft bump basis), sqrt(NRB) and /sqrt(NRB) cancel
    const float A = 1.14136f * 7.38905609893065f;   // 1.14136 * e^2
    const float inv_step = 17.0f / 5.0f;
    float emb[16];
    #pragma unroll
    for (int k = 0; k < 16; ++k) {
        float dd  = r * inv_step - (float)(k + 1);
        float d2v = dd * dd;
        float arg = -2.0f * __builtin_amdgcn_rcpf(1.0f - d2v);
        float val = A * __expf(arg);
        emb[k] = (d2v < 1.0f) ? val : 0.0f;
    }

    // --- h = silu(emb @ W1) : W1 rows read with uniform addresses ----------
    float h[64];
    #pragma unroll
    for (int i = 0; i < 64; ++i) h[i] = 0.f;
    #pragma unroll
    for (int k = 0; k < 16; ++k) {
        const float ek = emb[k];
        const float* w1row = W1 + k * 64;
        #pragma unroll
        for (int i = 0; i < 64; ++i) h[i] = fmaf(ek, w1row[i], h[i]);
    }
    #pragma unroll
    for (int i = 0; i < 64; ++i) {
        float z = h[i];
        h[i] = z * __builtin_amdgcn_rcpf(1.0f + __expf(-z));
    }

    // --- fused  w = h @ W2  +  tensor-product consumption ------------------
    // w columns: [0,256) w00 (u=cc), [256,384) w01, [384,448) w10, [448,576) w11
    float out0[16], t01[8], o1b[24];
    #pragma unroll
    for (int v = 0; v < 16; ++v) out0[v] = 0.f;
    #pragma unroll
    for (int v = 0; v < 8;  ++v) t01[v]  = 0.f;
    #pragma unroll
    for (int v = 0; v < 24; ++v) o1b[v]  = 0.f;

    #pragma unroll 1
    for (int cc = 0; cc < 36; ++cc) {
        float wch[16];
        #pragma unroll
        for (int jj = 0; jj < 16; ++jj) wch[jj] = 0.f;

        const float* w2base = W2 + cc * 16;   // uniform across the wave
        #pragma unroll
        for (int i = 0; i < 64; ++i) {
            const float hv = h[i];
            const float* row = w2base + i * 576;
            #pragma unroll
            for (int jj = 0; jj < 16; ++jj)
                wch[jj] = fmaf(hv, row[jj], wch[jj]);
        }

        if (cc < 16) {                      // w00: out0[v] += w00[u][v]*x0[u]
            float x0u = myx[cc];
            #pragma unroll
            for (int v = 0; v < 16; ++v) out0[v] = fmaf(wch[v], x0u, out0[v]);
        } else if (cc < 24) {               // w01: t01[v] += w01[u][v]*x0[u]
            int u0 = (cc - 16) * 2;
            float xa = myx[u0], xb = myx[u0 + 1];
            #pragma unroll
            for (int v = 0; v < 8; ++v) {
                t01[v] = fmaf(wch[v],     xa, t01[v]);
                t01[v] = fmaf(wch[8 + v], xb, t01[v]);
            }
        } else if (cc < 28) {               // w10: o1b[v][k] += w10[u][v]*x1[u][k]
            int u0 = (cc - 24) * 2;
            float xa0 = myx[16+3*u0+0], xa1 = myx[16+3*u0+1], xa2 = myx[16+3*u0+2];
            float xb0 = myx[16+3*u0+3], xb1 = myx[16+3*u0+4], xb2 = myx[16+3*u0+5];
            #pragma unroll
            for (int v = 0; v < 8; ++v) {
                o1b[3*v+0] = fmaf(wch[v], xa0, fmaf(wch[8+v], xb0, o1b[3*v+0]));
                o1b[3*v+1] = fmaf(wch[v], xa1, fmaf(wch[8+v], xb1, o1b[3*v+1]));
                o1b[3*v+2] = fmaf(wch[v], xa2, fmaf(wch[8+v], xb2, o1b[3*v+2]));
            }
        } else {                            // w11: out0[v] += w11[u][v]*dot2[u]
            float du = myx[40 + (cc - 28)];
            #pragma unroll
            for (int v = 0; v < 16; ++v) out0[v] = fmaf(wch[v], du, out0[v]);
        }
    }

    // --- epilogue: scale and scatter ---------------------------------------
    // S = (1/8 from w) * (1/sqrt(24) fan) * (1/4 neighbor norm)
    const float S = 1.0f / (32.0f * 4.898979485566356f);
    float* op = f_out + (size_t)d * 40;
    #pragma unroll
    for (int v = 0; v < 16; ++v) atomicAdd(&op[v], S * out0[v]);
    #pragma unroll
    for (int v = 0; v < 8; ++v) {
        float t = t01[v];
        atomicAdd(&op[16+3*v+0], S * fmaf(t, shx, o1b[3*v+0]));
        atomicAdd(&op[16+3*v+1], S * fmaf(t, shy, o1b[3*v+1]));
        atomicAdd(&op[16+3*v+2], S * fmaf(t, shz, o1b[3*v+2]));
    }
}

extern "C" void kernel_launch(void* const* d_in, const int* in_sizes, int n_in,
                              void* d_out, int out_size, void* d_ws, size_t ws_size,
                              hipStream_t stream) {
    const float* pos  = (const float*)d_in[0];
    const float* f_in = (const float*)d_in[1];
    const int*   esrc = (const int*)  d_in[2];
    const int*   edst = (const int*)  d_in[3];
    const float* W1   = (const float*)d_in[4];
    const float* W2   = (const float*)d_in[5];
    float* out = (float*)d_out;

    const int n4 = (N_NODES * DIM_F) / 4;   // 500000 float4s
    zero_out_kernel<<<(n4 + 255) / 256, 256, 0, stream>>>((float4*)out, n4);

    const int blocks = (N_EDGES + 255) / 256;   // 3125 exactly
    conv_kernel<<<blocks, 256, 0, stream>>>(pos, f_in, esrc, edst, W1, W2, out);
}

// Round 2
// 393.443 us; speedup vs baseline: 5.3109x; 5.3109x over previous
//
#include <hip/hip_runtime.h>

#define N_NODES 50000
#define N_EDGES 800000

typedef short  bf16x8 __attribute__((ext_vector_type(8)));
typedef float  f32x4  __attribute__((ext_vector_type(4)));

__device__ __forceinline__ unsigned short f2bf(float f) {
    unsigned u = __float_as_uint(f);
    u += 0x7FFF + ((u >> 16) & 1);          // RNE
    return (unsigned short)(u >> 16);
}

// ---------------------------------------------------------------------------
// Kernel 0: zero the output (harness poisons d_out with 0xAA)
// ---------------------------------------------------------------------------
__global__ void zero_out_kernel(float4* __restrict__ p, int n4) {
    int i = blockIdx.x * blockDim.x + threadIdx.x;
    if (i < n4) p[i] = make_float4(0.f, 0.f, 0.f, 0.f);
}

// ---------------------------------------------------------------------------
// Kernel 1: pack W2 (64x576 f32) into bf16 B-fragment order in d_ws.
// B-frag for (nt, ks): lane L holds B[k = ks*32 + (L>>4)*8 + j][n = nt*16 + (L&15)],
// j = 0..7 contiguous. Flat index: ((nt*2+ks)*64 + L)*8 + j.
// ---------------------------------------------------------------------------
__global__ void prep_w2_kernel(const float* __restrict__ W2,
                               unsigned short* __restrict__ wsB) {
    int gid = blockIdx.x * 256 + threadIdx.x;      // 36864 total
    if (gid >= 36864) return;
    int j    = gid & 7;
    int lane = (gid >> 3) & 63;
    int ks   = (gid >> 9) & 1;
    int nt   = gid >> 10;
    int k = ks * 32 + (lane >> 4) * 8 + j;
    int n = nt * 16 + (lane & 15);
    wsB[gid] = f2bf(W2[k * 576 + n]);
}

// ---------------------------------------------------------------------------
// Kernel 2: fused conv. Block = 256 = 4 independent waves; wave = 64 edges.
// Phase 1 (per lane = per edge): geometry, emb, h = silu(emb@W1) scalar.
// Phase 2: h -> LDS (A-frag layout), w = h@W2 via mfma_f32_16x16x32_bf16,
//          w-tiles roundtrip per-wave LDS, scalar tensor-product consumption
//          with x held in VGPRs (paths fully unrolled).
// Phase 3: outputs transposed through LDS -> lane-contiguous atomics.
// ---------------------------------------------------------------------------
__global__ __launch_bounds__(256, 2) void conv_kernel(
    const float* __restrict__ pos,
    const float* __restrict__ f_in,
    const int*   __restrict__ esrc,
    const int*   __restrict__ edst,
    const float* __restrict__ W1,
    const unsigned short* __restrict__ wsB,
    float*       __restrict__ f_out)
{
    // per-wave scratch, reused 3x:
    //   h-stage : 64 edges x 72 bf16 (stride-padded) = 9216 B
    //   w-tile  : 64 edges x 20 f32 (stride-padded)  = 5120 B
    //   out-tile: 64 edges x 44 f32 (stride-padded)  = 11264 B
    __shared__ __align__(16) char smem[4][11264];
    const int tid  = threadIdx.x;
    const int wave = tid >> 6;
    const int lane = tid & 63;
    const int e     = blockIdx.x * 256 + tid;
    const int wbase = blockIdx.x * 256 + wave * 64;
    char*  my  = smem[wave];
    float* shf = (float*)my;

    const int s = esrc[e];
    const int d = edst[e];

    // --- geometry -----------------------------------------------------------
    float px = pos[3*d+0] - pos[3*s+0];
    float py = pos[3*d+1] - pos[3*s+1];
    float pz = pos[3*d+2] - pos[3*s+2];
    float r  = sqrtf(px*px + py*py + pz*pz + 1e-12f);
    float inv_r = __builtin_amdgcn_rcpf(r);
    float ux = px*inv_r, uy = py*inv_r, uz = pz*inv_r;
    const float SQ3 = 1.7320508075688772f;
    float shx = SQ3*ux, shy = SQ3*uy, shz = SQ3*uz;

    // --- x = f_in[src] into VGPRs ------------------------------------------
    float x0[16], x1[24], dot[8];
    {
        const float4* xg4 = reinterpret_cast<const float4*>(f_in + (size_t)s * 40);
        float xr[40];
        #pragma unroll
        for (int q8 = 0; q8 < 10; ++q8) {
            float4 v = xg4[q8];
            xr[4*q8+0] = v.x; xr[4*q8+1] = v.y; xr[4*q8+2] = v.z; xr[4*q8+3] = v.w;
        }
        #pragma unroll
        for (int i = 0; i < 16; ++i) x0[i] = xr[i];
        #pragma unroll
        for (int i = 0; i < 24; ++i) x1[i] = xr[16+i];
        #pragma unroll
        for (int u = 0; u < 8; ++u)
            dot[u] = x1[3*u+0]*ux + x1[3*u+1]*uy + x1[3*u+2]*uz;  // = inv_s3*(x1.sh1)
    }

    // --- radial embedding ---------------------------------------------------
    const float A = 1.14136f * 7.38905609893065f;   // 1.14136 * e^2
    const float inv_step = 17.0f / 5.0f;
    float emb[16];
    #pragma unroll
    for (int k = 0; k < 16; ++k) {
        float dd  = r * inv_step - (float)(k + 1);
        float d2v = dd * dd;
        float arg = -2.0f * __builtin_amdgcn_rcpf(1.0f - d2v);
        float val = A * __expf(arg);
        emb[k] = (d2v < 1.0f) ? val : 0.0f;
    }

    // --- h = silu(emb @ W1) -------------------------------------------------
    float h[64];
    #pragma unroll
    for (int i = 0; i < 64; ++i) h[i] = 0.f;
    #pragma unroll
    for (int k = 0; k < 16; ++k) {
        const float ek = emb[k];
        const float* w1row = W1 + k * 64;
        #pragma unroll
        for (int i = 0; i < 64; ++i) h[i] = fmaf(ek, w1row[i], h[i]);
    }
    #pragma unroll
    for (int i = 0; i < 64; ++i) {
        float z = h[i];
        h[i] = z * __builtin_amdgcn_rcpf(1.0f + __expf(-z));
    }

    // --- stage h -> LDS in [edge][k] bf16, row stride 72 bf16 (144 B) ------
    {
        unsigned int hp[32];
        #pragma unroll
        for (int i = 0; i < 32; ++i)
            hp[i] = (unsigned)f2bf(h[2*i]) | ((unsigned)f2bf(h[2*i+1]) << 16);
        uint4* hrow = (uint4*)(my + lane * 144);
        #pragma unroll
        for (int g = 0; g < 8; ++g)
            hrow[g] = make_uint4(hp[4*g], hp[4*g+1], hp[4*g+2], hp[4*g+3]);
    }
    asm volatile("s_waitcnt lgkmcnt(0)" ::: "memory");

    // --- load A fragments (then h-region is dead, aliased by w-tiles) ------
    const int q   = lane >> 4;
    const int col = lane & 15;
    bf16x8 aF[4][2];
    #pragma unroll
    for (int mt = 0; mt < 4; ++mt)
        #pragma unroll
        for (int ks = 0; ks < 2; ++ks)
            aF[mt][ks] = *(const bf16x8*)(my + (mt*16 + col)*144 + q*16 + ks*64);

    // --- accumulators -------------------------------------------------------
    float out0[16], t01[8], o1b[24];
    #pragma unroll
    for (int v = 0; v < 16; ++v) out0[v] = 0.f;
    #pragma unroll
    for (int v = 0; v < 8;  ++v) t01[v]  = 0.f;
    #pragma unroll
    for (int v = 0; v < 24; ++v) o1b[v]  = 0.f;

    const bf16x8* wsBv = (const bf16x8*)wsB;
    bf16x8 bc0 = wsBv[lane];        // nt=0, ks=0
    bf16x8 bc1 = wsBv[64 + lane];   // nt=0, ks=1
    bf16x8 bn0 = {}, bn1 = {};
    float wch[16];

    // One N-tile: prefetch next B-frags, 8 MFMAs, C-tiles -> LDS (stride 20),
    // wait, read this lane's edge row (16 w values).
#define GEMM_CHUNK(NT) { \
    if ((NT) + 1 < 36) { \
        bn0 = wsBv[((NT)+1)*128 + lane]; \
        bn1 = wsBv[((NT)+1)*128 + 64 + lane]; \
    } \
    f32x4 w0 = {0.f,0.f,0.f,0.f}, w1 = {0.f,0.f,0.f,0.f}; \
    f32x4 w2 = {0.f,0.f,0.f,0.f}, w3 = {0.f,0.f,0.f,0.f}; \
    w0 = __builtin_amdgcn_mfma_f32_16x16x32_bf16(aF[0][0], bc0, w0, 0,0,0); \
    w1 = __builtin_amdgcn_mfma_f32_16x16x32_bf16(aF[1][0], bc0, w1, 0,0,0); \
    w2 = __builtin_amdgcn_mfma_f32_16x16x32_bf16(aF[2][0], bc0, w2, 0,0,0); \
    w3 = __builtin_amdgcn_mfma_f32_16x16x32_bf16(aF[3][0], bc0, w3, 0,0,0); \
    w0 = __builtin_amdgcn_mfma_f32_16x16x32_bf16(aF[0][1], bc1, w0, 0,0,0); \
    w1 = __builtin_amdgcn_mfma_f32_16x16x32_bf16(aF[1][1], bc1, w1, 0,0,0); \
    w2 = __builtin_amdgcn_mfma_f32_16x16x32_bf16(aF[2][1], bc1, w2, 0,0,0); \
    w3 = __builtin_amdgcn_mfma_f32_16x16x32_bf16(aF[3][1], bc1, w3, 0,0,0); \
    { float* wp = shf + q*80 + col; \
      wp[0]   = w0[0]; wp[20]  = w0[1]; wp[40]  = w0[2]; wp[60]  = w0[3]; \
      wp[320] = w1[0]; wp[340] = w1[1]; wp[360] = w1[2]; wp[380] = w1[3]; \
      wp[640] = w2[0]; wp[660] = w2[1]; wp[680] = w2[2]; wp[700] = w2[3]; \
      wp[960] = w3[0]; wp[980] = w3[1]; wp[1000]= w3[2]; wp[1020]= w3[3]; } \
    asm volatile("s_waitcnt lgkmcnt(0)" ::: "memory"); \
    { const float4* rp = (const float4*)(shf + lane*20); \
      float4 r0 = rp[0], r1 = rp[1], r2 = rp[2], r3 = rp[3]; \
      wch[0]=r0.x; wch[1]=r0.y; wch[2]=r0.z; wch[3]=r0.w; \
      wch[4]=r1.x; wch[5]=r1.y; wch[6]=r1.z; wch[7]=r1.w; \
      wch[8]=r2.x; wch[9]=r2.y; wch[10]=r2.z; wch[11]=r2.w; \
      wch[12]=r3.x; wch[13]=r3.y; wch[14]=r3.z; wch[15]=r3.w; } \
    bc0 = bn0; bc1 = bn1; }

    // --- path w00: tiles 0..15, out0[v] += w00[u][v] * x0[u] ---------------
    #pragma unroll
    for (int u = 0; u < 16; ++u) {
        GEMM_CHUNK(u);
        const float xv = x0[u];
        #pragma unroll
        for (int v = 0; v < 16; ++v) out0[v] = fmaf(wch[v], xv, out0[v]);
    }
    // --- path w01: tiles 16..23, t01[v] += w01[u][v] * x0[u] ---------------
    #pragma unroll
    for (int t = 0; t < 8; ++t) {
        GEMM_CHUNK(16 + t);
        const float xa = x0[2*t], xb = x0[2*t+1];
        #pragma unroll
        for (int v = 0; v < 8; ++v)
            t01[v] = fmaf(wch[v], xa, fmaf(wch[8+v], xb, t01[v]));
    }
    // --- path w10: tiles 24..27, o1b[v][k] += w10[u][v] * x1[u][k] ---------
    #pragma unroll
    for (int t = 0; t < 4; ++t) {
        GEMM_CHUNK(24 + t);
        const int u0 = 2*t;
        const float xa0 = x1[3*u0+0], xa1 = x1[3*u0+1], xa2 = x1[3*u0+2];
        const float xb0 = x1[3*u0+3], xb1 = x1[3*u0+4], xb2 = x1[3*u0+5];
        #pragma unroll
        for (int v = 0; v < 8; ++v) {
            o1b[3*v+0] = fmaf(wch[v], xa0, fmaf(wch[8+v], xb0, o1b[3*v+0]));
            o1b[3*v+1] = fmaf(wch[v], xa1, fmaf(wch[8+v], xb1, o1b[3*v+1]));
            o1b[3*v+2] = fmaf(wch[v], xa2, fmaf(wch[8+v], xb2, o1b[3*v+2]));
        }
    }
    // --- path w11: tiles 28..35, out0[v] += w11[u][v] * dot[u] -------------
    #pragma unroll
    for (int u = 0; u < 8; ++u) {
        GEMM_CHUNK(28 + u);
        const float dv = dot[u];
        #pragma unroll
        for (int v = 0; v < 16; ++v) out0[v] = fmaf(wch[v], dv, out0[v]);
    }
#undef GEMM_CHUNK

    // --- epilogue: scale, transpose through LDS, lane-contiguous atomics ---
    const float S = 1.0f / (32.0f * 4.898979485566356f);
    float fo[40];
    #pragma unroll
    for (int v = 0; v < 16; ++v) fo[v] = S * out0[v];
    #pragma unroll
    for (int v = 0; v < 8; ++v) {
        fo[16+3*v+0] = S * fmaf(t01[v], shx, o1b[3*v+0]);
        fo[16+3*v+1] = S * fmaf(t01[v], shy, o1b[3*v+1]);
        fo[16+3*v+2] = S * fmaf(t01[v], shz, o1b[3*v+2]);
    }
    {   // out-tile: stride 44 floats per edge
        float4* orow = (float4*)(shf + lane * 44);
        #pragma unroll
        for (int g = 0; g < 10; ++g)
            orow[g] = make_float4(fo[4*g], fo[4*g+1], fo[4*g+2], fo[4*g+3]);
    }
    asm volatile("s_waitcnt lgkmcnt(0)" ::: "memory");
    #pragma unroll 4
    for (int it = 0; it < 40; ++it) {
        int p  = it * 64 + lane;
        int ee = (p * 52429) >> 21;      // p / 40, exact for p < 4096
        int c  = p - ee * 40;
        float v = shf[ee * 44 + c];
        int dd = edst[wbase + ee];
        atomicAdd(f_out + (size_t)dd * 40 + c, v);
    }
}

extern "C" void kernel_launch(void* const* d_in, const int* in_sizes, int n_in,
                              void* d_out, int out_size, void* d_ws, size_t ws_size,
                              hipStream_t stream) {
    const float* pos  = (const float*)d_in[0];
    const float* f_in = (const float*)d_in[1];
    const int*   esrc = (const int*)  d_in[2];
    const int*   edst = (const int*)  d_in[3];
    const float* W1   = (const float*)d_in[4];
    const float* W2   = (const float*)d_in[5];
    float* out = (float*)d_out;
    unsigned short* wsB = (unsigned short*)d_ws;   // 36864 bf16 = 72 KiB

    const int n4 = (N_NODES * 40) / 4;
    zero_out_kernel<<<(n4 + 255) / 256, 256, 0, stream>>>((float4*)out, n4);
    prep_w2_kernel<<<144, 256, 0, stream>>>(W2, wsB);

    conv_kernel<<<N_EDGES / 256, 256, 0, stream>>>(pos, f_in, esrc, edst, W1, wsB, out);
}